// Round 2
// baseline (11618.077 us; speedup 1.0000x reference)
//
#include <hip/hip_runtime.h>
#include <hip/hip_fp16.h>

#define DS 256   // state_dim
#define DA 16    // act_dim
#define DH 30    // horizon
#define DHY 64   // hyper_dim
#define DB 64    // batch
#define DT 64    // seq len

// ---------------- setup kernels ----------------

__global__ __launch_bounds__(64) void k_hdist(const float* __restrict__ z,
                                              const float* __restrict__ tau,
                                              const float* __restrict__ tauw,
                                              float* __restrict__ h_dist) {
  const int bb = threadIdx.x;
  if (bb >= DB) return;
  float x = tau[0];
  for (int hy = 0; hy < DHY; ++hy) x = fmaf(z[bb * DHY + hy], tauw[hy], x);
  x = fminf(fmaxf(x, -8.f), 8.f);
  const float rate = __expf(x);
  const float lr = x;
  float lp[DH];
  float lg = 0.f;
  float mx = -1e30f;
  #pragma unroll
  for (int h = 0; h < DH; ++h) {
    const float ks = (float)(h + 1);
    lg += __logf(ks);
    lp[h] = ks * lr - rate - lg;
    mx = fmaxf(mx, lp[h]);
  }
  float sum = 0.f;
  #pragma unroll
  for (int h = 0; h < DH; ++h) { lp[h] = __expf(lp[h] - mx); sum += lp[h]; }
  const float inv = 1.f / sum;
  #pragma unroll
  for (int h = 0; h < DH; ++h) h_dist[bb * DH + h] = lp[h] * inv;
}

// zero out_pi (T*B*A = 65536 = 256 wgs * 256) and cnt
__global__ __launch_bounds__(256) void k_zero(float* __restrict__ out_pi,
                                              unsigned int* __restrict__ cnt) {
  const int i = blockIdx.x * 256 + threadIdx.x;
  out_pi[i] = 0.f;
  if (i < DB) cnt[i] = 0u;
}

// transition[b,ki,j] = softmax_j(w[ki,j] + sum_hy z[b,hy]*wofs[(ki*S+j),hy]), fp16.
// one wg per ki; batch 8 b's per reduction round (barriers 128 -> 16).
__global__ __launch_bounds__(256) void k_trans(const float* __restrict__ w,
                                               const float* __restrict__ wofs,
                                               const float* __restrict__ z,
                                               __half* __restrict__ trans) {
  const int ki = blockIdx.x;
  const int j = threadIdx.x;
  float wr[DHY];
  {
    const float4* w4 = reinterpret_cast<const float4*>(wofs + ((size_t)ki * DS + j) * DHY);
    #pragma unroll
    for (int q = 0; q < DHY / 4; ++q) {
      const float4 v = w4[q];
      wr[4 * q] = v.x; wr[4 * q + 1] = v.y; wr[4 * q + 2] = v.z; wr[4 * q + 3] = v.w;
    }
  }
  const float wbase = w[(size_t)ki * DS + j];
  __shared__ float red[4][8];
  const int lane = threadIdx.x & 63;
  const int wid = threadIdx.x >> 6;
  __half* tout = trans + (size_t)ki * DS + j;
  for (int bg = 0; bg < DB; bg += 8) {
    float e8[8];
    #pragma unroll
    for (int b8 = 0; b8 < 8; ++b8) {
      const float* zb = z + (size_t)(bg + b8) * DHY;  // wave-uniform -> scalar loads
      float a0 = wbase, a1 = 0.f, a2 = 0.f, a3 = 0.f;
      #pragma unroll
      for (int hy = 0; hy < DHY; hy += 4) {
        a0 = fmaf(zb[hy],     wr[hy],     a0);
        a1 = fmaf(zb[hy + 1], wr[hy + 1], a1);
        a2 = fmaf(zb[hy + 2], wr[hy + 2], a2);
        a3 = fmaf(zb[hy + 3], wr[hy + 3], a3);
      }
      e8[b8] = __expf((a0 + a1) + (a2 + a3));  // logits small: no max-subtract needed
    }
    #pragma unroll
    for (int b8 = 0; b8 < 8; ++b8) {
      float v = e8[b8];
      #pragma unroll
      for (int o = 32; o >= 1; o >>= 1) v += __shfl_xor(v, o, 64);
      if (lane == 0) red[wid][b8] = v;
    }
    __syncthreads();
    #pragma unroll
    for (int b8 = 0; b8 < 8; ++b8) {
      const float s = red[0][b8] + red[1][b8] + red[2][b8] + red[3][b8];
      tout[(size_t)(bg + b8) * (DA * DS * DS)] = __float2half(e8[b8] / s);
    }
    __syncthreads();
  }
}

// ---------------- persistent fused scan ----------------
// grid = 512 wgs: bb = wgid&63, jt = wgid>>6 (same-b wgs stride 64 -> same XCD under %8).
// Each wg owns j-chunk [jt*32, jt*32+32) of s_next and h-range [jt*4, jt*4+4) of plan.
// Cross-wg data per step: 32 floats of s_next per wg + one atomic counter per b.
__global__ __launch_bounds__(256, 2) void k_scan(
    const __half* __restrict__ trans,
    const float* __restrict__ logp_o,
    const float* __restrict__ logp_u,
    const float* __restrict__ value,
    const float* __restrict__ h_dist,
    const float* __restrict__ b0,
    float* __restrict__ s_buf,          // [2][B][S]
    unsigned int* __restrict__ cnt,     // [B], zeroed by k_zero
    float* __restrict__ out_b,
    float* __restrict__ out_pi) {
  const int bb = blockIdx.x & 63;
  const int jt = blockIdx.x >> 6;
  const int tid = threadIdx.x;
  const int lane = tid & 63;
  const int wid = tid >> 6;

  __shared__ __align__(16) float wv[DA * DS];  // a[k]*b[i]
  __shared__ __align__(16) float bl[DS];       // current belief (per-wg copy)
  __shared__ float aa[DA];
  __shared__ float hd[DH + 2];
  __shared__ float red4[4][32];
  __shared__ float redm[4], reds[4];
  __shared__ float api[DA];

  bl[tid] = b0[bb * DS + tid];
  if (tid < DH) hd[tid] = h_dist[bb * DH + tid];
  __syncthreads();

  const int jg = tid & 3;        // j-group of 8 within 32-chunk
  const int rb = tid >> 2;       // row 0..63 per pass
  const __half* tb = trans + (size_t)bb * (DA * DS * DS) + jt * 32 + jg * 8;

  for (int t = 0; t < DT; ++t) {
    // ---- alpha_a inline: softmax over 16 actions ----
    if (tid < DA) {
      const float lg = logp_u[((size_t)t * DB + bb) * DA + tid];
      float m = lg;
      #pragma unroll
      for (int o = 8; o >= 1; o >>= 1) m = fmaxf(m, __shfl_xor(m, o, 16));
      const float e = __expf(lg - m);
      float s = e;
      #pragma unroll
      for (int o = 8; o >= 1; o >>= 1) s += __shfl_xor(s, o, 16);
      aa[tid] = e / s;
    }
    __syncthreads();
    #pragma unroll
    for (int r = tid; r < DA * DS; r += 256) wv[r] = aa[r >> 8] * bl[r & 255];
    __syncthreads();

    // ---- phase A: partial s_next over all (k,i) rows, 32 j's ----
    float acc[8] = {0.f, 0.f, 0.f, 0.f, 0.f, 0.f, 0.f, 0.f};
    #pragma unroll 16
    for (int it = 0; it < 64; ++it) {
      const int r = it * 64 + rb;
      const float wgt = wv[r];
      union { int4 i4; __half2 h2[4]; } u;
      u.i4 = *reinterpret_cast<const int4*>(tb + (size_t)r * DS);
      #pragma unroll
      for (int q = 0; q < 4; ++q) {
        const float2 f = __half22float2(u.h2[q]);
        acc[2 * q]     = fmaf(wgt, f.x, acc[2 * q]);
        acc[2 * q + 1] = fmaf(wgt, f.y, acc[2 * q + 1]);
      }
    }
    #pragma unroll
    for (int q = 0; q < 8; ++q) {   // reduce over row bits (lane bits 2..5)
      acc[q] += __shfl_xor(acc[q], 4, 64);
      acc[q] += __shfl_xor(acc[q], 8, 64);
      acc[q] += __shfl_xor(acc[q], 16, 64);
      acc[q] += __shfl_xor(acc[q], 32, 64);
    }
    if (lane < 4) {
      #pragma unroll
      for (int q = 0; q < 8; ++q) red4[wid][(tid & 3) * 8 + q] = acc[q];
    }
    __syncthreads();
    if (tid < 32) {
      const float s = red4[0][tid] + red4[1][tid] + red4[2][tid] + red4[3][tid];
      s_buf[(size_t)(t & 1) * DB * DS + bb * DS + jt * 32 + tid] = s;
    }
    __threadfence();        // device-scope release of s_next chunk
    __syncthreads();
    if (tid == 0) {
      __hip_atomic_fetch_add(&cnt[bb], 1u, __ATOMIC_RELEASE, __HIP_MEMORY_SCOPE_AGENT);
      const unsigned int target = 8u * (unsigned int)(t + 1);
      while (__hip_atomic_load(&cnt[bb], __ATOMIC_ACQUIRE, __HIP_MEMORY_SCOPE_AGENT) < target)
        __builtin_amdgcn_s_sleep(2);
    }
    __syncthreads();
    __threadfence();

    // ---- phase B: belief update (all wgs redundantly) ----
    const float sv = __hip_atomic_load(&s_buf[(size_t)(t & 1) * DB * DS + bb * DS + tid],
                                       __ATOMIC_RELAXED, __HIP_MEMORY_SCOPE_AGENT);
    const float l = __logf(sv + 1e-6f) + logp_o[((size_t)t * DB + bb) * DS + tid];
    float m = l;
    #pragma unroll
    for (int o = 32; o >= 1; o >>= 1) m = fmaxf(m, __shfl_xor(m, o, 64));
    if (lane == 0) redm[wid] = m;
    __syncthreads();
    m = fmaxf(fmaxf(redm[0], redm[1]), fmaxf(redm[2], redm[3]));
    const float e = __expf(l - m);
    float v = e;
    #pragma unroll
    for (int o = 32; o >= 1; o >>= 1) v += __shfl_xor(v, o, 64);
    if (lane == 0) reds[wid] = v;
    if (tid < DA) api[tid] = 0.f;
    __syncthreads();
    const float s = reds[0] + reds[1] + reds[2] + reds[3];
    const float p = e / s;
    bl[tid] = p;
    if (jt == 0) out_b[((size_t)t * DB + bb) * DS + tid] = p;
    __syncthreads();

    // ---- plan: h in [jt*4, jt*4+4), (h,k) pairs on tid<128, dot split in half ----
    if (tid < 128) {
      const int hl = tid >> 5;
      const int k = (tid >> 1) & 15;
      const int half = tid & 1;
      const int h = jt * 4 + hl;
      float dot = 0.f;
      if (h < DH) {
        const float4* vr = reinterpret_cast<const float4*>(
            value + (((size_t)h * DB + bb) * DA + k) * DS) + half * 32;
        const float4* b4 = reinterpret_cast<const float4*>(bl) + half * 32;
        #pragma unroll 8
        for (int q = 0; q < 32; ++q) {
          const float4 a4 = vr[q];
          const float4 c4 = b4[q];
          dot += a4.x * c4.x + a4.y * c4.y + a4.z * c4.z + a4.w * c4.w;
        }
      }
      dot += __shfl_xor(dot, 1, 64);      // combine halves (lane bit 0)
      float mk = dot;                      // softmax over k (lane bits 1..4)
      #pragma unroll
      for (int o = 16; o >= 2; o >>= 1) mk = fmaxf(mk, __shfl_xor(mk, o, 64));
      const float ek = __expf(dot - mk);
      float sk = ek;
      #pragma unroll
      for (int o = 16; o >= 2; o >>= 1) sk += __shfl_xor(sk, o, 64);
      if (h < DH && half == 0) atomicAdd(&api[k], (ek / sk) * hd[h]);
    }
    __syncthreads();
    if (tid < DA) atomicAdd(&out_pi[((size_t)t * DB + bb) * DA + tid], api[tid]);
    __syncthreads();
  }
}

// ---------------- launch ----------------

extern "C" void kernel_launch(void* const* d_in, const int* in_sizes, int n_in,
                              void* d_out, int out_size, void* d_ws, size_t ws_size,
                              hipStream_t stream) {
  const float* logp_o = (const float*)d_in[0];
  const float* logp_u = (const float*)d_in[1];
  const float* value  = (const float*)d_in[2];
  const float* z      = (const float*)d_in[3];
  const float* b0     = (const float*)d_in[4];
  const float* w      = (const float*)d_in[5];
  const float* wofs   = (const float*)d_in[6];
  const float* tau    = (const float*)d_in[7];
  const float* tauw   = (const float*)d_in[8];

  char* ws = (char*)d_ws;
  size_t off = 0;
  __half* trans      = (__half*)(ws + off);       off += (size_t)DB * DA * DS * DS * sizeof(__half);
  float* s_buf       = (float*)(ws + off);        off += (size_t)2 * DB * DS * sizeof(float);
  unsigned int* cnt  = (unsigned int*)(ws + off); off += 256;
  float* h_dist      = (float*)(ws + off);        off += (size_t)DB * DH * sizeof(float) + 64;
  if (off > ws_size) return;

  float* out_b  = (float*)d_out;
  float* out_pi = out_b + (size_t)DT * DB * DS;

  k_zero<<<256, 256, 0, stream>>>(out_pi, cnt);
  k_hdist<<<1, 64, 0, stream>>>(z, tau, tauw, h_dist);
  k_trans<<<DA * DS, 256, 0, stream>>>(w, wofs, z, trans);
  k_scan<<<512, 256, 0, stream>>>(trans, logp_o, logp_u, value, h_dist, b0,
                                  s_buf, cnt, out_b, out_pi);
}

// Round 3
// 5727.106 us; speedup vs baseline: 2.0286x; 2.0286x over previous
//
#include <hip/hip_runtime.h>
#include <hip/hip_fp16.h>

#define DS 256   // state_dim
#define DA 16    // act_dim
#define DH 30    // horizon
#define DHY 64   // hyper_dim
#define DB 64    // batch
#define DT 64    // seq len

// ---------------- setup kernels ----------------

__global__ __launch_bounds__(64) void k_hdist(const float* __restrict__ z,
                                              const float* __restrict__ tau,
                                              const float* __restrict__ tauw,
                                              float* __restrict__ h_dist) {
  const int bb = threadIdx.x;
  if (bb >= DB) return;
  float x = tau[0];
  for (int hy = 0; hy < DHY; ++hy) x = fmaf(z[bb * DHY + hy], tauw[hy], x);
  x = fminf(fmaxf(x, -8.f), 8.f);
  const float rate = __expf(x);
  const float lr = x;
  float lp[DH];
  float lg = 0.f;
  float mx = -1e30f;
  #pragma unroll
  for (int h = 0; h < DH; ++h) {
    const float ks = (float)(h + 1);
    lg += __logf(ks);
    lp[h] = ks * lr - rate - lg;
    mx = fmaxf(mx, lp[h]);
  }
  float sum = 0.f;
  #pragma unroll
  for (int h = 0; h < DH; ++h) { lp[h] = __expf(lp[h] - mx); sum += lp[h]; }
  const float inv = 1.f / sum;
  #pragma unroll
  for (int h = 0; h < DH; ++h) h_dist[bb * DH + h] = lp[h] * inv;
}

__global__ __launch_bounds__(256) void k_zero(float* __restrict__ out_pi) {
  out_pi[blockIdx.x * 256 + threadIdx.x] = 0.f;
}

// value fp32 -> fp16 (n = DH*DB*DA*DS = 7864320, divisible by 4)
__global__ __launch_bounds__(256) void k_vconv(const float* __restrict__ v,
                                               __half* __restrict__ v16, int n4) {
  const int stride = gridDim.x * 256;
  for (int i = blockIdx.x * 256 + threadIdx.x; i < n4; i += stride) {
    const float4 f = reinterpret_cast<const float4*>(v)[i];
    __half2 h0 = __floats2half2_rn(f.x, f.y);
    __half2 h1 = __floats2half2_rn(f.z, f.w);
    reinterpret_cast<__half2*>(v16)[2 * i] = h0;
    reinterpret_cast<__half2*>(v16)[2 * i + 1] = h1;
  }
}

// transition[b,ki,j] = softmax_j(w[ki,j] + sum_hy z[b,hy]*wofs[(ki*S+j),hy]), fp16.
// one wg per ki; wr[64] kept in VGPRs (launch_bounds(256,1)); batch 16 b's per barrier round.
__global__ __launch_bounds__(256, 1) void k_trans(const float* __restrict__ w,
                                                  const float* __restrict__ wofs,
                                                  const float* __restrict__ z,
                                                  __half* __restrict__ trans) {
  const int ki = blockIdx.x;
  const int j = threadIdx.x;
  float wr[DHY];
  {
    const float4* w4 = reinterpret_cast<const float4*>(wofs + ((size_t)ki * DS + j) * DHY);
    #pragma unroll
    for (int q = 0; q < DHY / 4; ++q) {
      const float4 v = w4[q];
      wr[4 * q] = v.x; wr[4 * q + 1] = v.y; wr[4 * q + 2] = v.z; wr[4 * q + 3] = v.w;
    }
  }
  const float wbase = w[(size_t)ki * DS + j];
  __shared__ float zs[DB * DHY];  // 16 KB
  for (int tt = threadIdx.x; tt < DB * DHY; tt += 256) zs[tt] = z[tt];
  __shared__ float red[4][16];
  __syncthreads();
  const int lane = threadIdx.x & 63;
  const int wid = threadIdx.x >> 6;
  for (int bg = 0; bg < DB; bg += 16) {
    float e16[16];
    #pragma unroll
    for (int b16 = 0; b16 < 16; ++b16) {
      const float* zb = &zs[(bg + b16) * DHY];  // wave-uniform -> broadcast reads
      float a0 = wbase, a1 = 0.f, a2 = 0.f, a3 = 0.f;
      #pragma unroll
      for (int hy = 0; hy < DHY; hy += 4) {
        a0 = fmaf(zb[hy],     wr[hy],     a0);
        a1 = fmaf(zb[hy + 1], wr[hy + 1], a1);
        a2 = fmaf(zb[hy + 2], wr[hy + 2], a2);
        a3 = fmaf(zb[hy + 3], wr[hy + 3], a3);
      }
      e16[b16] = __expf((a0 + a1) + (a2 + a3));  // logits small: no max-subtract needed
    }
    #pragma unroll
    for (int b16 = 0; b16 < 16; ++b16) {
      float v = e16[b16];
      #pragma unroll
      for (int o = 32; o >= 1; o >>= 1) v += __shfl_xor(v, o, 64);
      if (lane == 0) red[wid][b16] = v;
    }
    __syncthreads();
    #pragma unroll
    for (int b16 = 0; b16 < 16; ++b16) {
      const float s = red[0][b16] + red[1][b16] + red[2][b16] + red[3][b16];
      trans[(size_t)(bg + b16) * (DA * DS * DS) + (size_t)ki * DS + j] =
          __float2half(e16[b16] / s);
    }
    __syncthreads();
  }
}

// ---------------- per-step kernel (65 launches; kernel boundary = global sync) ----------------
// grid = 512: bb = wgid&63, jt = wgid>>6 (same-b wgs stride 64 -> same XCD under %8).
// t in [0,64]. If t>0: finish step t-1 (belief softmax from s_buf[(t-1)&1] -> out_b, plan -> out_pi).
// If t<64: compute s_next(t) partial (j-chunk of 32) -> s_buf[t&1].
__global__ __launch_bounds__(256, 2) void k_step(
    const __half* __restrict__ trans,
    const float* __restrict__ logp_o,
    const float* __restrict__ logp_u,
    const __half* __restrict__ value16,
    const float* __restrict__ h_dist,
    const float* __restrict__ b0,
    float* __restrict__ s_buf,          // [2][B][S]
    float* __restrict__ out_b,
    float* __restrict__ out_pi,
    int t) {
  const int bb = blockIdx.x & 63;
  const int jt = blockIdx.x >> 6;
  const int tid = threadIdx.x;
  const int lane = tid & 63;
  const int wid = tid >> 6;

  __shared__ __align__(16) float wv[DA * DS];  // 16 KB
  __shared__ __align__(16) float bl[DS];
  __shared__ float aa[DA];
  __shared__ float redm[4], reds[4];
  __shared__ float red4[4][4][8];
  __shared__ float api[DA];

  if (t > 0) {
    const int tp = t - 1;
    // belief update (redundant in all 8 wgs of this b)
    const float sv = s_buf[(size_t)(tp & 1) * DB * DS + bb * DS + tid];
    const float l = __logf(sv + 1e-6f) + logp_o[((size_t)tp * DB + bb) * DS + tid];
    float m = l;
    #pragma unroll
    for (int o = 32; o >= 1; o >>= 1) m = fmaxf(m, __shfl_xor(m, o, 64));
    if (lane == 0) redm[wid] = m;
    __syncthreads();
    m = fmaxf(fmaxf(redm[0], redm[1]), fmaxf(redm[2], redm[3]));
    const float e = __expf(l - m);
    float v = e;
    #pragma unroll
    for (int o = 32; o >= 1; o >>= 1) v += __shfl_xor(v, o, 64);
    if (lane == 0) reds[wid] = v;
    if (tid < DA) api[tid] = 0.f;
    __syncthreads();
    const float p = e / (reds[0] + reds[1] + reds[2] + reds[3]);
    bl[tid] = p;
    if (jt == 0) out_b[((size_t)tp * DB + bb) * DS + tid] = p;
    __syncthreads();
    // plan: wave wid handles h = jt*4+wid; lane: k = lane>>2, quarter q = lane&3 (64 i each)
    const int h = jt * 4 + wid;
    const int k = lane >> 2;
    const int q = lane & 3;
    float dot = 0.f;
    if (h < DH) {
      const __half* vr = value16 + (((size_t)h * DB + bb) * DA + k) * DS + q * 64;
      const float* blq = bl + q * 64;
      #pragma unroll
      for (int ii = 0; ii < 64; ii += 8) {
        union { int4 i4; __half2 h2[4]; } u;
        u.i4 = *reinterpret_cast<const int4*>(vr + ii);
        const float4 c0 = *reinterpret_cast<const float4*>(blq + ii);
        const float4 c1 = *reinterpret_cast<const float4*>(blq + ii + 4);
        const float2 f0 = __half22float2(u.h2[0]);
        const float2 f1 = __half22float2(u.h2[1]);
        const float2 f2 = __half22float2(u.h2[2]);
        const float2 f3 = __half22float2(u.h2[3]);
        dot = fmaf(f0.x, c0.x, dot); dot = fmaf(f0.y, c0.y, dot);
        dot = fmaf(f1.x, c0.z, dot); dot = fmaf(f1.y, c0.w, dot);
        dot = fmaf(f2.x, c1.x, dot); dot = fmaf(f2.y, c1.y, dot);
        dot = fmaf(f3.x, c1.z, dot); dot = fmaf(f3.y, c1.w, dot);
      }
    }
    dot += __shfl_xor(dot, 1, 64);   // combine quarters
    dot += __shfl_xor(dot, 2, 64);
    float mk = dot;                   // softmax over k (lane bits 2..5)
    #pragma unroll
    for (int o = 4; o <= 32; o <<= 1) mk = fmaxf(mk, __shfl_xor(mk, o, 64));
    const float ek = __expf(dot - mk);
    float sk = ek;
    #pragma unroll
    for (int o = 4; o <= 32; o <<= 1) sk += __shfl_xor(sk, o, 64);
    if (h < DH && q == 0) atomicAdd(&api[k], (ek / sk) * h_dist[bb * DH + h]);
    __syncthreads();
    if (tid < DA) atomicAdd(&out_pi[((size_t)tp * DB + bb) * DA + tid], api[tid]);
  } else {
    bl[tid] = b0[bb * DS + tid];
  }
  __syncthreads();

  if (t < DT) {
    // alpha_a inline
    if (tid < DA) {
      const float lg = logp_u[((size_t)t * DB + bb) * DA + tid];
      float m = lg;
      #pragma unroll
      for (int o = 8; o >= 1; o >>= 1) m = fmaxf(m, __shfl_xor(m, o, 16));
      const float e = __expf(lg - m);
      float s = e;
      #pragma unroll
      for (int o = 8; o >= 1; o >>= 1) s += __shfl_xor(s, o, 16);
      aa[tid] = e / s;
    }
    __syncthreads();
    #pragma unroll
    for (int r = tid; r < DA * DS; r += 256) wv[r] = aa[r >> 8] * bl[r & 255];
    __syncthreads();
    // phase A: partial s_next over all 4096 (k,i) rows for 32 j's
    const int jg = tid & 3;        // j-group of 8
    const int rb = tid >> 2;       // 64 rows per pass
    const __half* tb = trans + (size_t)bb * (DA * DS * DS) + jt * 32 + jg * 8;
    float acc[8] = {0.f, 0.f, 0.f, 0.f, 0.f, 0.f, 0.f, 0.f};
    #pragma unroll 8
    for (int it = 0; it < 64; ++it) {
      const int r = it * 64 + rb;
      const float wgt = wv[r];
      union { int4 i4; __half2 h2[4]; } u;
      u.i4 = *reinterpret_cast<const int4*>(tb + (size_t)r * DS);
      #pragma unroll
      for (int qq = 0; qq < 4; ++qq) {
        const float2 f = __half22float2(u.h2[qq]);
        acc[2 * qq]     = fmaf(wgt, f.x, acc[2 * qq]);
        acc[2 * qq + 1] = fmaf(wgt, f.y, acc[2 * qq + 1]);
      }
    }
    #pragma unroll
    for (int q = 0; q < 8; ++q) {  // reduce over row bits (lane bits 2..5)
      acc[q] += __shfl_xor(acc[q], 4, 64);
      acc[q] += __shfl_xor(acc[q], 8, 64);
      acc[q] += __shfl_xor(acc[q], 16, 64);
      acc[q] += __shfl_xor(acc[q], 32, 64);
    }
    if (lane < 4) {
      #pragma unroll
      for (int q = 0; q < 8; ++q) red4[wid][lane][q] = acc[q];
    }
    __syncthreads();
    if (tid < 32) {
      const int jg2 = tid >> 3, q2 = tid & 7;
      const float s = red4[0][jg2][q2] + red4[1][jg2][q2] +
                      red4[2][jg2][q2] + red4[3][jg2][q2];
      s_buf[(size_t)(t & 1) * DB * DS + bb * DS + jt * 32 + jg2 * 8 + q2] = s;
    }
  }
}

// ---------------- launch ----------------

extern "C" void kernel_launch(void* const* d_in, const int* in_sizes, int n_in,
                              void* d_out, int out_size, void* d_ws, size_t ws_size,
                              hipStream_t stream) {
  const float* logp_o = (const float*)d_in[0];
  const float* logp_u = (const float*)d_in[1];
  const float* value  = (const float*)d_in[2];
  const float* z      = (const float*)d_in[3];
  const float* b0     = (const float*)d_in[4];
  const float* w      = (const float*)d_in[5];
  const float* wofs   = (const float*)d_in[6];
  const float* tau    = (const float*)d_in[7];
  const float* tauw   = (const float*)d_in[8];

  char* ws = (char*)d_ws;
  size_t off = 0;
  __half* trans   = (__half*)(ws + off); off += (size_t)DB * DA * DS * DS * sizeof(__half);
  float* s_buf    = (float*)(ws + off);  off += (size_t)2 * DB * DS * sizeof(float);
  __half* value16 = (__half*)(ws + off); off += (size_t)DH * DB * DA * DS * sizeof(__half);
  float* h_dist   = (float*)(ws + off);  off += (size_t)DB * DH * sizeof(float) + 64;
  if (off > ws_size) return;

  float* out_b  = (float*)d_out;
  float* out_pi = out_b + (size_t)DT * DB * DS;

  k_zero<<<256, 256, 0, stream>>>(out_pi);
  k_hdist<<<1, 64, 0, stream>>>(z, tau, tauw, h_dist);
  k_vconv<<<1024, 256, 0, stream>>>(value, value16, DH * DB * DA * DS / 4);
  k_trans<<<DA * DS, 256, 0, stream>>>(w, wofs, z, trans);
  for (int t = 0; t <= DT; ++t) {
    k_step<<<512, 256, 0, stream>>>(trans, logp_o, logp_u, value16, h_dist, b0,
                                    s_buf, out_b, out_pi, t);
  }
}

// Round 4
// 1990.037 us; speedup vs baseline: 5.8381x; 2.8779x over previous
//
#include <hip/hip_runtime.h>
#include <hip/hip_fp16.h>

#define DS 256   // state_dim
#define DA 16    // act_dim
#define DH 30    // horizon
#define DHY 64   // hyper_dim
#define DB 64    // batch
#define DT 64    // seq len

// ---------------- setup kernels ----------------

__global__ __launch_bounds__(64) void k_hdist(const float* __restrict__ z,
                                              const float* __restrict__ tau,
                                              const float* __restrict__ tauw,
                                              float* __restrict__ h_dist) {
  const int bb = threadIdx.x;
  if (bb >= DB) return;
  float x = tau[0];
  for (int hy = 0; hy < DHY; ++hy) x = fmaf(z[bb * DHY + hy], tauw[hy], x);
  x = fminf(fmaxf(x, -8.f), 8.f);
  const float rate = __expf(x);
  const float lr = x;
  float lp[DH];
  float lg = 0.f;
  float mx = -1e30f;
  #pragma unroll
  for (int h = 0; h < DH; ++h) {
    const float ks = (float)(h + 1);
    lg += __logf(ks);
    lp[h] = ks * lr - rate - lg;
    mx = fmaxf(mx, lp[h]);
  }
  float sum = 0.f;
  #pragma unroll
  for (int h = 0; h < DH; ++h) { lp[h] = __expf(lp[h] - mx); sum += lp[h]; }
  const float inv = 1.f / sum;
  #pragma unroll
  for (int h = 0; h < DH; ++h) h_dist[bb * DH + h] = lp[h] * inv;
}

__global__ __launch_bounds__(256) void k_zero(float* __restrict__ out_pi) {
  out_pi[blockIdx.x * 256 + threadIdx.x] = 0.f;
}

// value fp32 -> fp16 (n4 = DH*DB*DA*DS/4)
__global__ __launch_bounds__(256) void k_vconv(const float* __restrict__ v,
                                               __half* __restrict__ v16, int n4) {
  const int stride = gridDim.x * 256;
  for (int i = blockIdx.x * 256 + threadIdx.x; i < n4; i += stride) {
    const float4 f = reinterpret_cast<const float4*>(v)[i];
    reinterpret_cast<__half2*>(v16)[2 * i]     = __floats2half2_rn(f.x, f.y);
    reinterpret_cast<__half2*>(v16)[2 * i + 1] = __floats2half2_rn(f.z, f.w);
  }
}

// transition[b,ki,j] = softmax_j(w[ki,j] + sum_hy z[b,hy]*wofs[(ki*S+j),hy]), fp16.
// one wg per ki. Registers hold acc[16] (per-b) — compile-time indexed; wofs row is
// STREAMED 16 floats at a time (reloaded per b-group from L1; never a 64-reg array).
// z reads are wave-uniform -> scalar loads + FMA-with-SGPR.
__global__ __launch_bounds__(256) void k_trans(const float* __restrict__ w,
                                               const float* __restrict__ wofs,
                                               const float* __restrict__ z,
                                               __half* __restrict__ trans) {
  const int ki = blockIdx.x;
  const int j = threadIdx.x;
  const int lane = j & 63;
  const int wid = j >> 6;
  const float wbase = w[(size_t)ki * DS + j];
  const float4* wrow4 = reinterpret_cast<const float4*>(wofs + ((size_t)ki * DS + j) * DHY);
  const float4* z4 = reinterpret_cast<const float4*>(z);
  __shared__ float red[4][16];

  for (int bg = 0; bg < 4; ++bg) {
    float acc[16];
    #pragma unroll
    for (int b = 0; b < 16; ++b) acc[b] = wbase;
    #pragma unroll
    for (int hc = 0; hc < 4; ++hc) {
      const float4 wa = wrow4[hc * 4 + 0];
      const float4 wb = wrow4[hc * 4 + 1];
      const float4 wc = wrow4[hc * 4 + 2];
      const float4 wd = wrow4[hc * 4 + 3];
      #pragma unroll
      for (int b = 0; b < 16; ++b) {
        const int zi = (bg * 16 + b) * 16 + hc * 4;  // float4 index into z
        const float4 za = z4[zi + 0];
        const float4 zb = z4[zi + 1];
        const float4 zc = z4[zi + 2];
        const float4 zd = z4[zi + 3];
        float a = acc[b];
        a = fmaf(za.x, wa.x, a); a = fmaf(za.y, wa.y, a);
        a = fmaf(za.z, wa.z, a); a = fmaf(za.w, wa.w, a);
        a = fmaf(zb.x, wb.x, a); a = fmaf(zb.y, wb.y, a);
        a = fmaf(zb.z, wb.z, a); a = fmaf(zb.w, wb.w, a);
        a = fmaf(zc.x, wc.x, a); a = fmaf(zc.y, wc.y, a);
        a = fmaf(zc.z, wc.z, a); a = fmaf(zc.w, wc.w, a);
        a = fmaf(zd.x, wd.x, a); a = fmaf(zd.y, wd.y, a);
        a = fmaf(zd.z, wd.z, a); a = fmaf(zd.w, wd.w, a);
        acc[b] = a;
      }
    }
    // softmax over j (256 threads) for these 16 b's; logits small -> no max-subtract
    #pragma unroll
    for (int b = 0; b < 16; ++b) acc[b] = __expf(acc[b]);
    #pragma unroll
    for (int b = 0; b < 16; ++b) {
      float v = acc[b];
      #pragma unroll
      for (int o = 32; o >= 1; o >>= 1) v += __shfl_xor(v, o, 64);
      if (lane == 0) red[wid][b] = v;
    }
    __syncthreads();
    #pragma unroll
    for (int b = 0; b < 16; ++b) {
      const float s = red[0][b] + red[1][b] + red[2][b] + red[3][b];
      trans[(size_t)(bg * 16 + b) * (DA * DS * DS) + (size_t)ki * DS + j] =
          __float2half(acc[b] / s);
    }
    __syncthreads();
  }
}

// ---------------- per-step kernel (65 launches; kernel boundary = global sync) ----------------
// grid = 512: bb = wgid&63, jt = wgid>>6 (same-b wgs stride 64 -> same XCD under %8).
// t in [0,64]. If t>0: finish step t-1 (belief softmax from s_buf[(t-1)&1] -> out_b, plan -> out_pi).
// If t<64: compute s_next(t) partial (j-chunk of 32) -> s_buf[t&1].
__global__ __launch_bounds__(256, 2) void k_step(
    const __half* __restrict__ trans,
    const float* __restrict__ logp_o,
    const float* __restrict__ logp_u,
    const __half* __restrict__ value16,
    const float* __restrict__ h_dist,
    const float* __restrict__ b0,
    float* __restrict__ s_buf,          // [2][B][S]
    float* __restrict__ out_b,
    float* __restrict__ out_pi,
    int t) {
  const int bb = blockIdx.x & 63;
  const int jt = blockIdx.x >> 6;
  const int tid = threadIdx.x;
  const int lane = tid & 63;
  const int wid = tid >> 6;

  __shared__ __align__(16) float wv[DA * DS];  // 16 KB
  __shared__ __align__(16) float bl[DS];
  __shared__ float aa[DA];
  __shared__ float redm[4], reds[4];
  __shared__ float red4[4][4][8];
  __shared__ float api[DA];

  if (t > 0) {
    const int tp = t - 1;
    // belief update (redundant in all 8 wgs of this b)
    const float sv = s_buf[(size_t)(tp & 1) * DB * DS + bb * DS + tid];
    const float l = __logf(sv + 1e-6f) + logp_o[((size_t)tp * DB + bb) * DS + tid];
    float m = l;
    #pragma unroll
    for (int o = 32; o >= 1; o >>= 1) m = fmaxf(m, __shfl_xor(m, o, 64));
    if (lane == 0) redm[wid] = m;
    __syncthreads();
    m = fmaxf(fmaxf(redm[0], redm[1]), fmaxf(redm[2], redm[3]));
    const float e = __expf(l - m);
    float v = e;
    #pragma unroll
    for (int o = 32; o >= 1; o >>= 1) v += __shfl_xor(v, o, 64);
    if (lane == 0) reds[wid] = v;
    if (tid < DA) api[tid] = 0.f;
    __syncthreads();
    const float p = e / (reds[0] + reds[1] + reds[2] + reds[3]);
    bl[tid] = p;
    if (jt == 0) out_b[((size_t)tp * DB + bb) * DS + tid] = p;
    __syncthreads();
    // plan: wave wid handles h = jt*4+wid; lane: k = lane>>2, quarter q = lane&3 (64 i each)
    const int h = jt * 4 + wid;
    const int k = lane >> 2;
    const int q = lane & 3;
    float dot = 0.f;
    if (h < DH) {
      const __half* vr = value16 + (((size_t)h * DB + bb) * DA + k) * DS + q * 64;
      const float* blq = bl + q * 64;
      #pragma unroll
      for (int ii = 0; ii < 64; ii += 8) {
        union { int4 i4; __half2 h2[4]; } u;
        u.i4 = *reinterpret_cast<const int4*>(vr + ii);
        const float4 c0 = *reinterpret_cast<const float4*>(blq + ii);
        const float4 c1 = *reinterpret_cast<const float4*>(blq + ii + 4);
        const float2 f0 = __half22float2(u.h2[0]);
        const float2 f1 = __half22float2(u.h2[1]);
        const float2 f2 = __half22float2(u.h2[2]);
        const float2 f3 = __half22float2(u.h2[3]);
        dot = fmaf(f0.x, c0.x, dot); dot = fmaf(f0.y, c0.y, dot);
        dot = fmaf(f1.x, c0.z, dot); dot = fmaf(f1.y, c0.w, dot);
        dot = fmaf(f2.x, c1.x, dot); dot = fmaf(f2.y, c1.y, dot);
        dot = fmaf(f3.x, c1.z, dot); dot = fmaf(f3.y, c1.w, dot);
      }
    }
    dot += __shfl_xor(dot, 1, 64);   // combine quarters
    dot += __shfl_xor(dot, 2, 64);
    float mk = dot;                   // softmax over k (lane bits 2..5)
    #pragma unroll
    for (int o = 4; o <= 32; o <<= 1) mk = fmaxf(mk, __shfl_xor(mk, o, 64));
    const float ek = __expf(dot - mk);
    float sk = ek;
    #pragma unroll
    for (int o = 4; o <= 32; o <<= 1) sk += __shfl_xor(sk, o, 64);
    if (h < DH && q == 0) atomicAdd(&api[k], (ek / sk) * h_dist[bb * DH + h]);
    __syncthreads();
    if (tid < DA) atomicAdd(&out_pi[((size_t)tp * DB + bb) * DA + tid], api[tid]);
  } else {
    bl[tid] = b0[bb * DS + tid];
  }
  __syncthreads();

  if (t < DT) {
    // alpha_a inline
    if (tid < DA) {
      const float lg = logp_u[((size_t)t * DB + bb) * DA + tid];
      float m = lg;
      #pragma unroll
      for (int o = 8; o >= 1; o >>= 1) m = fmaxf(m, __shfl_xor(m, o, 16));
      const float e = __expf(lg - m);
      float s = e;
      #pragma unroll
      for (int o = 8; o >= 1; o >>= 1) s += __shfl_xor(s, o, 16);
      aa[tid] = e / s;
    }
    __syncthreads();
    #pragma unroll
    for (int r = tid; r < DA * DS; r += 256) wv[r] = aa[r >> 8] * bl[r & 255];
    __syncthreads();
    // phase A: partial s_next over all 4096 (k,i) rows for 32 j's
    const int jg = tid & 3;        // j-group of 8
    const int rb = tid >> 2;       // 64 rows per pass
    const __half* tb = trans + (size_t)bb * (DA * DS * DS) + jt * 32 + jg * 8;
    float acc[8] = {0.f, 0.f, 0.f, 0.f, 0.f, 0.f, 0.f, 0.f};
    #pragma unroll 8
    for (int it = 0; it < 64; ++it) {
      const int r = it * 64 + rb;
      const float wgt = wv[r];
      union { int4 i4; __half2 h2[4]; } u;
      u.i4 = *reinterpret_cast<const int4*>(tb + (size_t)r * DS);
      #pragma unroll
      for (int qq = 0; qq < 4; ++qq) {
        const float2 f = __half22float2(u.h2[qq]);
        acc[2 * qq]     = fmaf(wgt, f.x, acc[2 * qq]);
        acc[2 * qq + 1] = fmaf(wgt, f.y, acc[2 * qq + 1]);
      }
    }
    #pragma unroll
    for (int q = 0; q < 8; ++q) {  // reduce over row bits (lane bits 2..5)
      acc[q] += __shfl_xor(acc[q], 4, 64);
      acc[q] += __shfl_xor(acc[q], 8, 64);
      acc[q] += __shfl_xor(acc[q], 16, 64);
      acc[q] += __shfl_xor(acc[q], 32, 64);
    }
    if (lane < 4) {
      #pragma unroll
      for (int q = 0; q < 8; ++q) red4[wid][lane][q] = acc[q];
    }
    __syncthreads();
    if (tid < 32) {
      const int jg2 = tid >> 3, q2 = tid & 7;
      const float s = red4[0][jg2][q2] + red4[1][jg2][q2] +
                      red4[2][jg2][q2] + red4[3][jg2][q2];
      s_buf[(size_t)(t & 1) * DB * DS + bb * DS + jt * 32 + jg2 * 8 + q2] = s;
    }
  }
}

// ---------------- launch ----------------

extern "C" void kernel_launch(void* const* d_in, const int* in_sizes, int n_in,
                              void* d_out, int out_size, void* d_ws, size_t ws_size,
                              hipStream_t stream) {
  const float* logp_o = (const float*)d_in[0];
  const float* logp_u = (const float*)d_in[1];
  const float* value  = (const float*)d_in[2];
  const float* z      = (const float*)d_in[3];
  const float* b0     = (const float*)d_in[4];
  const float* w      = (const float*)d_in[5];
  const float* wofs   = (const float*)d_in[6];
  const float* tau    = (const float*)d_in[7];
  const float* tauw   = (const float*)d_in[8];

  char* ws = (char*)d_ws;
  size_t off = 0;
  __half* trans   = (__half*)(ws + off); off += (size_t)DB * DA * DS * DS * sizeof(__half);
  float* s_buf    = (float*)(ws + off);  off += (size_t)2 * DB * DS * sizeof(float);
  __half* value16 = (__half*)(ws + off); off += (size_t)DH * DB * DA * DS * sizeof(__half);
  float* h_dist   = (float*)(ws + off);  off += (size_t)DB * DH * sizeof(float) + 64;
  if (off > ws_size) return;

  float* out_b  = (float*)d_out;
  float* out_pi = out_b + (size_t)DT * DB * DS;

  k_zero<<<256, 256, 0, stream>>>(out_pi);
  k_hdist<<<1, 64, 0, stream>>>(z, tau, tauw, h_dist);
  k_vconv<<<1024, 256, 0, stream>>>(value, value16, DH * DB * DA * DS / 4);
  k_trans<<<DA * DS, 256, 0, stream>>>(w, wofs, z, trans);
  for (int t = 0; t <= DT; ++t) {
    k_step<<<512, 256, 0, stream>>>(trans, logp_o, logp_u, value16, h_dist, b0,
                                    s_buf, out_b, out_pi, t);
  }
}

// Round 5
// 1782.424 us; speedup vs baseline: 6.5181x; 1.1165x over previous
//
#include <hip/hip_runtime.h>
#include <hip/hip_fp16.h>

#define DS 256   // state_dim
#define DA 16    // act_dim
#define DH 30    // horizon
#define DHY 64   // hyper_dim
#define DB 64    // batch
#define DT 64    // seq len

// ---------------- setup kernels ----------------

__global__ __launch_bounds__(64) void k_hdist(const float* __restrict__ z,
                                              const float* __restrict__ tau,
                                              const float* __restrict__ tauw,
                                              float* __restrict__ h_dist) {
  const int bb = threadIdx.x;
  if (bb >= DB) return;
  float x = tau[0];
  for (int hy = 0; hy < DHY; ++hy) x = fmaf(z[bb * DHY + hy], tauw[hy], x);
  x = fminf(fmaxf(x, -8.f), 8.f);
  const float rate = __expf(x);
  const float lr = x;
  float lp[DH];
  float lg = 0.f;
  float mx = -1e30f;
  #pragma unroll
  for (int h = 0; h < DH; ++h) {
    const float ks = (float)(h + 1);
    lg += __logf(ks);
    lp[h] = ks * lr - rate - lg;
    mx = fmaxf(mx, lp[h]);
  }
  float sum = 0.f;
  #pragma unroll
  for (int h = 0; h < DH; ++h) { lp[h] = __expf(lp[h] - mx); sum += lp[h]; }
  const float inv = 1.f / sum;
  #pragma unroll
  for (int h = 0; h < DH; ++h) h_dist[bb * DH + h] = lp[h] * inv;
}

__global__ __launch_bounds__(256) void k_zero(float* __restrict__ out_pi) {
  out_pi[blockIdx.x * 256 + threadIdx.x] = 0.f;
}

// value fp32 -> fp16 (n4 = DH*DB*DA*DS/4)
__global__ __launch_bounds__(256) void k_vconv(const float* __restrict__ v,
                                               __half* __restrict__ v16, int n4) {
  const int stride = gridDim.x * 256;
  for (int i = blockIdx.x * 256 + threadIdx.x; i < n4; i += stride) {
    const float4 f = reinterpret_cast<const float4*>(v)[i];
    reinterpret_cast<__half2*>(v16)[2 * i]     = __floats2half2_rn(f.x, f.y);
    reinterpret_cast<__half2*>(v16)[2 * i + 1] = __floats2half2_rn(f.z, f.w);
  }
}

// transition[b,ki,j] = softmax_j(w[ki,j] + sum_hy z[b,hy]*wofs[(ki*S+j),hy]), fp16.
// grid = A*S*4: one wg per (ki, bg); each wg handles 16 b's. No serial bg loop,
// acc[16] compile-time indexed, wofs row streamed 16 floats at a time.
__global__ __launch_bounds__(256) void k_trans(const float* __restrict__ w,
                                               const float* __restrict__ wofs,
                                               const float* __restrict__ z,
                                               __half* __restrict__ trans) {
  const int ki = blockIdx.x >> 2;
  const int bg = blockIdx.x & 3;
  const int j = threadIdx.x;
  const int lane = j & 63;
  const int wid = j >> 6;
  const float wbase = w[(size_t)ki * DS + j];
  const float4* wrow4 = reinterpret_cast<const float4*>(wofs + ((size_t)ki * DS + j) * DHY);
  const float4* z4 = reinterpret_cast<const float4*>(z);
  __shared__ float red[4][16];

  float acc[16];
  #pragma unroll
  for (int b = 0; b < 16; ++b) acc[b] = wbase;
  #pragma unroll
  for (int hc = 0; hc < 4; ++hc) {
    const float4 wa = wrow4[hc * 4 + 0];
    const float4 wb = wrow4[hc * 4 + 1];
    const float4 wc = wrow4[hc * 4 + 2];
    const float4 wd = wrow4[hc * 4 + 3];
    #pragma unroll
    for (int b = 0; b < 16; ++b) {
      const int zi = (bg * 16 + b) * 16 + hc * 4;  // float4 index into z (wave-uniform)
      const float4 za = z4[zi + 0];
      const float4 zb = z4[zi + 1];
      const float4 zc = z4[zi + 2];
      const float4 zd = z4[zi + 3];
      float a = acc[b];
      a = fmaf(za.x, wa.x, a); a = fmaf(za.y, wa.y, a);
      a = fmaf(za.z, wa.z, a); a = fmaf(za.w, wa.w, a);
      a = fmaf(zb.x, wb.x, a); a = fmaf(zb.y, wb.y, a);
      a = fmaf(zb.z, wb.z, a); a = fmaf(zb.w, wb.w, a);
      a = fmaf(zc.x, wc.x, a); a = fmaf(zc.y, wc.y, a);
      a = fmaf(zc.z, wc.z, a); a = fmaf(zc.w, wc.w, a);
      a = fmaf(zd.x, wd.x, a); a = fmaf(zd.y, wd.y, a);
      a = fmaf(zd.z, wd.z, a); a = fmaf(zd.w, wd.w, a);
      acc[b] = a;
    }
  }
  // softmax over j (256 threads) for these 16 b's; logits small -> no max-subtract
  #pragma unroll
  for (int b = 0; b < 16; ++b) acc[b] = __expf(acc[b]);
  #pragma unroll
  for (int b = 0; b < 16; ++b) {
    float v = acc[b];
    #pragma unroll
    for (int o = 32; o >= 1; o >>= 1) v += __shfl_xor(v, o, 64);
    if (lane == 0) red[wid][b] = v;
  }
  __syncthreads();
  #pragma unroll
  for (int b = 0; b < 16; ++b) {
    const float s = red[0][b] + red[1][b] + red[2][b] + red[3][b];
    trans[(size_t)(bg * 16 + b) * (DA * DS * DS) + (size_t)ki * DS + j] =
        __float2half(acc[b] / s);
  }
}

// ---------------- per-step kernel (65 launches; kernel boundary = global sync) ----------------
// grid = 512: bb = wgid&63, jt = wgid>>6.
// t in [0,64]. If t>0: finish step t-1 (belief softmax -> out_b, plan -> out_pi).
// If t<64: compute s_next(t) partial (j-chunk of 32) -> s_buf[t&1].
union HV { int4 i4; __half2 h2[4]; };

#define K_LD(I) (*reinterpret_cast<const int4*>(tb + (size_t)((I) * 64 + rb) * DS))
#define K_FMA(QV, I) {                                              \
    HV u; u.i4 = (QV);                                              \
    const float wgt = wv[(I) * 64 + rb];                            \
    const float2 f0 = __half22float2(u.h2[0]);                      \
    const float2 f1 = __half22float2(u.h2[1]);                      \
    const float2 f2 = __half22float2(u.h2[2]);                      \
    const float2 f3 = __half22float2(u.h2[3]);                      \
    acc[0] = fmaf(wgt, f0.x, acc[0]); acc[1] = fmaf(wgt, f0.y, acc[1]); \
    acc[2] = fmaf(wgt, f1.x, acc[2]); acc[3] = fmaf(wgt, f1.y, acc[3]); \
    acc[4] = fmaf(wgt, f2.x, acc[4]); acc[5] = fmaf(wgt, f2.y, acc[5]); \
    acc[6] = fmaf(wgt, f3.x, acc[6]); acc[7] = fmaf(wgt, f3.y, acc[7]); }

__global__ __launch_bounds__(256, 2) void k_step(
    const __half* __restrict__ trans,
    const float* __restrict__ logp_o,
    const float* __restrict__ logp_u,
    const __half* __restrict__ value16,
    const float* __restrict__ h_dist,
    const float* __restrict__ b0,
    float* __restrict__ s_buf,          // [2][B][S]
    float* __restrict__ out_b,
    float* __restrict__ out_pi,
    int t) {
  const int bb = blockIdx.x & 63;
  const int jt = blockIdx.x >> 6;
  const int tid = threadIdx.x;
  const int lane = tid & 63;
  const int wid = tid >> 6;

  __shared__ __align__(16) float wv[DA * DS];  // 16 KB
  __shared__ __align__(16) float bl[DS];
  __shared__ float aa[DA];
  __shared__ float redm[4], reds[4];
  __shared__ float red4[4][4][8];
  __shared__ float api[DA];

  if (t > 0) {
    const int tp = t - 1;
    // belief update (redundant in all 8 wgs of this b)
    const float sv = s_buf[(size_t)(tp & 1) * DB * DS + bb * DS + tid];
    const float l = __logf(sv + 1e-6f) + logp_o[((size_t)tp * DB + bb) * DS + tid];
    float m = l;
    #pragma unroll
    for (int o = 32; o >= 1; o >>= 1) m = fmaxf(m, __shfl_xor(m, o, 64));
    if (lane == 0) redm[wid] = m;
    __syncthreads();
    m = fmaxf(fmaxf(redm[0], redm[1]), fmaxf(redm[2], redm[3]));
    const float e = __expf(l - m);
    float v = e;
    #pragma unroll
    for (int o = 32; o >= 1; o >>= 1) v += __shfl_xor(v, o, 64);
    if (lane == 0) reds[wid] = v;
    if (tid < DA) api[tid] = 0.f;
    __syncthreads();
    const float p = e / (reds[0] + reds[1] + reds[2] + reds[3]);
    bl[tid] = p;
    if (jt == 0) out_b[((size_t)tp * DB + bb) * DS + tid] = p;
    __syncthreads();
    // plan: wave wid handles h = jt*4+wid; lane: k = lane>>2, quarter q = lane&3 (64 i each)
    const int h = jt * 4 + wid;
    const int k = lane >> 2;
    const int q = lane & 3;
    float dot = 0.f;
    if (h < DH) {
      const __half* vr = value16 + (((size_t)h * DB + bb) * DA + k) * DS + q * 64;
      const float* blq = bl + q * 64;
      #pragma unroll
      for (int ii = 0; ii < 64; ii += 8) {
        HV u;
        u.i4 = *reinterpret_cast<const int4*>(vr + ii);
        const float4 c0 = *reinterpret_cast<const float4*>(blq + ii);
        const float4 c1 = *reinterpret_cast<const float4*>(blq + ii + 4);
        const float2 f0 = __half22float2(u.h2[0]);
        const float2 f1 = __half22float2(u.h2[1]);
        const float2 f2 = __half22float2(u.h2[2]);
        const float2 f3 = __half22float2(u.h2[3]);
        dot = fmaf(f0.x, c0.x, dot); dot = fmaf(f0.y, c0.y, dot);
        dot = fmaf(f1.x, c0.z, dot); dot = fmaf(f1.y, c0.w, dot);
        dot = fmaf(f2.x, c1.x, dot); dot = fmaf(f2.y, c1.y, dot);
        dot = fmaf(f3.x, c1.z, dot); dot = fmaf(f3.y, c1.w, dot);
      }
    }
    dot += __shfl_xor(dot, 1, 64);   // combine quarters
    dot += __shfl_xor(dot, 2, 64);
    float mk = dot;                   // softmax over k (lane bits 2..5)
    #pragma unroll
    for (int o = 4; o <= 32; o <<= 1) mk = fmaxf(mk, __shfl_xor(mk, o, 64));
    const float ek = __expf(dot - mk);
    float sk = ek;
    #pragma unroll
    for (int o = 4; o <= 32; o <<= 1) sk += __shfl_xor(sk, o, 64);
    if (h < DH && q == 0) atomicAdd(&api[k], (ek / sk) * h_dist[bb * DH + h]);
    __syncthreads();
    if (tid < DA) atomicAdd(&out_pi[((size_t)tp * DB + bb) * DA + tid], api[tid]);
  } else {
    bl[tid] = b0[bb * DS + tid];
  }
  __syncthreads();

  if (t < DT) {
    // alpha_a inline
    if (tid < DA) {
      const float lg = logp_u[((size_t)t * DB + bb) * DA + tid];
      float m = lg;
      #pragma unroll
      for (int o = 8; o >= 1; o >>= 1) m = fmaxf(m, __shfl_xor(m, o, 16));
      const float e = __expf(lg - m);
      float s = e;
      #pragma unroll
      for (int o = 8; o >= 1; o >>= 1) s += __shfl_xor(s, o, 16);
      aa[tid] = e / s;
    }
    __syncthreads();
    #pragma unroll
    for (int r = tid; r < DA * DS; r += 256) wv[r] = aa[r >> 8] * bl[r & 255];
    __syncthreads();
    // phase A: partial s_next over all 4096 (k,i) rows for 32 j's.
    // 8-deep explicit software pipeline: Q0..Q7 named regs, each consume re-issues
    // its slot's load 8 iterations ahead -> 8 loads (8 KB) in flight per wave.
    const int jg = tid & 3;        // j-group of 8
    const int rb = tid >> 2;       // 64 rows per pass
    const __half* tb = trans + (size_t)bb * (DA * DS * DS) + jt * 32 + jg * 8;
    float acc[8] = {0.f, 0.f, 0.f, 0.f, 0.f, 0.f, 0.f, 0.f};
    int4 Q0 = K_LD(0), Q1 = K_LD(1), Q2 = K_LD(2), Q3 = K_LD(3);
    int4 Q4 = K_LD(4), Q5 = K_LD(5), Q6 = K_LD(6), Q7 = K_LD(7);
    #pragma unroll
    for (int it = 0; it < 56; it += 8) {
      K_FMA(Q0, it + 0); Q0 = K_LD(it + 8);
      K_FMA(Q1, it + 1); Q1 = K_LD(it + 9);
      K_FMA(Q2, it + 2); Q2 = K_LD(it + 10);
      K_FMA(Q3, it + 3); Q3 = K_LD(it + 11);
      K_FMA(Q4, it + 4); Q4 = K_LD(it + 12);
      K_FMA(Q5, it + 5); Q5 = K_LD(it + 13);
      K_FMA(Q6, it + 6); Q6 = K_LD(it + 14);
      K_FMA(Q7, it + 7); Q7 = K_LD(it + 15);
    }
    K_FMA(Q0, 56); K_FMA(Q1, 57); K_FMA(Q2, 58); K_FMA(Q3, 59);
    K_FMA(Q4, 60); K_FMA(Q5, 61); K_FMA(Q6, 62); K_FMA(Q7, 63);
    #pragma unroll
    for (int q = 0; q < 8; ++q) {  // reduce over row bits (lane bits 2..5)
      acc[q] += __shfl_xor(acc[q], 4, 64);
      acc[q] += __shfl_xor(acc[q], 8, 64);
      acc[q] += __shfl_xor(acc[q], 16, 64);
      acc[q] += __shfl_xor(acc[q], 32, 64);
    }
    if (lane < 4) {
      #pragma unroll
      for (int q = 0; q < 8; ++q) red4[wid][lane][q] = acc[q];
    }
    __syncthreads();
    if (tid < 32) {
      const int jg2 = tid >> 3, q2 = tid & 7;
      const float s = red4[0][jg2][q2] + red4[1][jg2][q2] +
                      red4[2][jg2][q2] + red4[3][jg2][q2];
      s_buf[(size_t)(t & 1) * DB * DS + bb * DS + jt * 32 + jg2 * 8 + q2] = s;
    }
  }
}

// ---------------- launch ----------------

extern "C" void kernel_launch(void* const* d_in, const int* in_sizes, int n_in,
                              void* d_out, int out_size, void* d_ws, size_t ws_size,
                              hipStream_t stream) {
  const float* logp_o = (const float*)d_in[0];
  const float* logp_u = (const float*)d_in[1];
  const float* value  = (const float*)d_in[2];
  const float* z      = (const float*)d_in[3];
  const float* b0     = (const float*)d_in[4];
  const float* w      = (const float*)d_in[5];
  const float* wofs   = (const float*)d_in[6];
  const float* tau    = (const float*)d_in[7];
  const float* tauw   = (const float*)d_in[8];

  char* ws = (char*)d_ws;
  size_t off = 0;
  __half* trans   = (__half*)(ws + off); off += (size_t)DB * DA * DS * DS * sizeof(__half);
  float* s_buf    = (float*)(ws + off);  off += (size_t)2 * DB * DS * sizeof(float);
  __half* value16 = (__half*)(ws + off); off += (size_t)DH * DB * DA * DS * sizeof(__half);
  float* h_dist   = (float*)(ws + off);  off += (size_t)DB * DH * sizeof(float) + 64;
  if (off > ws_size) return;

  float* out_b  = (float*)d_out;
  float* out_pi = out_b + (size_t)DT * DB * DS;

  k_zero<<<256, 256, 0, stream>>>(out_pi);
  k_hdist<<<1, 64, 0, stream>>>(z, tau, tauw, h_dist);
  k_vconv<<<1024, 256, 0, stream>>>(value, value16, DH * DB * DA * DS / 4);
  k_trans<<<DA * DS * 4, 256, 0, stream>>>(w, wofs, z, trans);
  for (int t = 0; t <= DT; ++t) {
    k_step<<<512, 256, 0, stream>>>(trans, logp_o, logp_u, value16, h_dist, b0,
                                    s_buf, out_b, out_pi, t);
  }
}